// Round 28
// baseline (398.372 us; speedup 1.0000x reference)
//
#include <hip/hip_runtime.h>
#include <math.h>

namespace {

constexpr int B_ = 64;
constexpr int C_ = 192;
constexpr int H_ = 56;
constexpr int W_ = 56;
constexpr int HW_ = H_ * W_;          // 3136
constexpr int CHW_ = C_ * HW_;        // 602112
constexpr float PI_F = 3.14159265358979323846f;

typedef __attribute__((ext_vector_type(8))) short short8;
typedef __attribute__((ext_vector_type(4))) short short4v;
typedef __attribute__((ext_vector_type(4))) float f32x4;

typedef const __attribute__((address_space(1))) unsigned int g_u32;
typedef __attribute__((address_space(3))) unsigned int l_u32;

__device__ inline unsigned short f2bf(float f) {
  union { float f; unsigned u; } v{f};
  unsigned r = v.u + 0x7FFFu + ((v.u >> 16) & 1u);
  return (unsigned short)(r >> 16);
}
__device__ inline float bf2f(unsigned short s) {
  union { unsigned u; float f; } v;
  v.u = ((unsigned)s) << 16;
  return v.f;
}

// XOR swizzle for [row][c] bf16 tiles, row stride 200 elems (16B granular)
__device__ inline int swz(int row) { return ((row >> 1) & 7) << 3; }

// ---------------------------------------------------------------------------
// K0 (v2): DCT-II basis, bf16, BOTH orientations, padded [64][72] LDS image.
// ---------------------------------------------------------------------------
__global__ void k_tables(unsigned short* __restrict__ cosb,
                         unsigned short* __restrict__ cosbT) {
  int i = blockIdx.x * 256 + threadIdx.x;
  if (i >= 64 * 72) return;
  int r = i / 72, q = i - r * 72;
  unsigned short v0 = 0, v1 = 0;
  if (r < 56 && q < 56) {
    float a0 = cosf(((float)r * (((float)q + 0.5f) / 56.0f)) * PI_F) * 0.18898223650461362f;
    if (r == 0) a0 *= 0.7071067811865476f;
    v0 = f2bf(a0);
    float a1 = cosf(((float)q * (((float)r + 0.5f) / 56.0f)) * PI_F) * 0.18898223650461362f;
    if (q == 0) a1 *= 0.7071067811865476f;
    v1 = f2bf(a1);
  }
  cosb[i] = v0;   // [n][h]
  cosbT[i] = v1;  // [h][n]
}

// ---------------------------------------------------------------------------
// K_wexp: wexp[c][hw] = exp(-relu(fe@tok_w+tok_b) * (n^2+m^2))
// ---------------------------------------------------------------------------
__global__ __launch_bounds__(192) void k_wexp(const float* __restrict__ fe,
                                              const float* __restrict__ tkw,
                                              const float* __restrict__ tkb,
                                              float* __restrict__ wexp) {
  __shared__ float sfe[16][C_];
  int hw0 = blockIdx.x * 16;
  int t = threadIdx.x;
  for (int p = 0; p < 16; ++p) sfe[p][t] = fe[(size_t)(hw0 + p) * C_ + t];
  __syncthreads();
  float acc[16];
#pragma unroll
  for (int p = 0; p < 16; ++p) acc[p] = 0.f;
  for (int i = 0; i < C_; ++i) {
    float wv = tkw[i * C_ + t];
#pragma unroll
    for (int p = 0; p < 16; ++p) acc[p] = fmaf(sfe[p][i], wv, acc[p]);
  }
  float bias = tkb[t];
  const float step = PI_F / 56.0f;
#pragma unroll
  for (int p = 0; p < 16; ++p) {
    int hw = hw0 + p;
    int hh = hw / W_;
    int ww = hw - hh * W_;
    float nh = step * (float)hh;
    float nm = step * (float)ww;
    float a = nh * nh + nm * nm;
    float k = fmaxf(acc[p] + bias, 0.0f);
    wexp[(size_t)t * HW_ + hw] = expf(-k * a);
  }
}

// ---------------------------------------------------------------------------
// K_prep_w: lwT[j][c] = bf16(lin_w[c][j]), owT[j][c] = bf16(out_w[c][j])
// ---------------------------------------------------------------------------
__global__ __launch_bounds__(256) void k_prep_w(const float* __restrict__ lw,
                                                const float* __restrict__ ow,
                                                unsigned short* __restrict__ lwT,
                                                unsigned short* __restrict__ owT) {
  int i = blockIdx.x * 256 + threadIdx.x;
  if (i < 384 * 192) {
    int j = i / 192, c = i - j * 192;
    lwT[i] = f2bf(lw[c * 384 + j]);
  } else if (i < 384 * 192 + 192 * 192) {
    int k = i - 384 * 192;
    int j = k / 192, c = k - j * 192;
    owT[k] = f2bf(ow[c * 192 + j]);
  }
}

// ---------------------------------------------------------------------------
// K1 (v8): depthwise 3x3 conv via async global_load_lds staging, 48 ch/block.
// ---------------------------------------------------------------------------
__global__ __launch_bounds__(256) void k_convt(const float* __restrict__ x,
                                               const float* __restrict__ dww,
                                               const float* __restrict__ dwb,
                                               unsigned short* __restrict__ yTc) {
  __shared__ float win[48 * 192];
  __shared__ float swt[48 * 9];
  __shared__ float sbi[48];
  int tid = threadIdx.x;
  int pt = blockIdx.x, qr = blockIdx.y, b = blockIdx.z;
  int c0 = qr * 48;
  for (int i = tid; i < 48 * 9; i += 256) swt[i] = dww[c0 * 9 + i];
  if (tid < 48) sbi[tid] = dwb[c0 + tid];

  int lane = tid & 63, wv = tid >> 6;
  int ws = pt * 64 - 60;
  int srcf = ws + lane * 4;
  srcf = srcf < 0 ? 0 : (srcf > HW_ - 4 ? HW_ - 4 : srcf);
  const float* xb = x + (size_t)b * CHW_ + (size_t)c0 * HW_;
  if (lane < 48) {
    for (int cc = wv; cc < 48; cc += 4) {
      __builtin_amdgcn_global_load_lds((g_u32*)(xb + (size_t)cc * HW_ + srcf),
                                       (l_u32*)(win + cc * 192), 16, 0, 0);
    }
  }
  __syncthreads();  // drains vmcnt

  int p = tid & 63, chg = tid >> 6;
  int pos = pt * 64 + p;
  int h = pos / 56, w = pos - h * 56;
  float mN = h > 0 ? 1.f : 0.f, mP = h < 55 ? 1.f : 0.f;
  float mL = w > 0 ? 1.f : 0.f, mR = w < 55 ? 1.f : 0.f;
  int base = p + 60;
  int l0 = chg * 12;
  unsigned short r[12];
#pragma unroll
  for (int e = 0; e < 12; ++e) {
    int cc = l0 + e;
    const float* wr = &win[cc * 192];
    const float* w9 = &swt[cc * 9];
    float a = sbi[cc];
    {  // row -1
      float wa = w9[0] * mN, wb = w9[1] * mN, wc = w9[2] * mN;
      float v0 = wr[base - 57] * mL, v1 = wr[base - 56], v2 = wr[base - 55] * mR;
      a = fmaf(v0, wa, fmaf(v1, wb, fmaf(v2, wc, a)));
    }
    {  // row 0
      float v0 = wr[base - 1] * mL, v1 = wr[base], v2 = wr[base + 1] * mR;
      a = fmaf(v0, w9[3], fmaf(v1, w9[4], fmaf(v2, w9[5], a)));
    }
    {  // row +1
      float wa = w9[6] * mP, wb = w9[7] * mP, wc = w9[8] * mP;
      float v0 = wr[base + 55] * mL, v1 = wr[base + 56], v2 = wr[base + 57] * mR;
      a = fmaf(v0, wa, fmaf(v1, wb, fmaf(v2, wc, a)));
    }
    r[e] = f2bf(a);
  }
  int chunkA = (c0 >> 3) + (l0 >> 3);
  size_t blk = (size_t)b * 24;
  if ((chg & 1) == 0) {
    short8 v8 = {(short)r[0], (short)r[1], (short)r[2], (short)r[3],
                 (short)r[4], (short)r[5], (short)r[6], (short)r[7]};
    short4v v4 = {(short)r[8], (short)r[9], (short)r[10], (short)r[11]};
    *(short8*)&yTc[((blk + chunkA) * HW_ + pos) * 8] = v8;
    *(short4v*)&yTc[((blk + chunkA + 1) * HW_ + pos) * 8] = v4;
  } else {
    short4v v4 = {(short)r[0], (short)r[1], (short)r[2], (short)r[3]};
    short8 v8 = {(short)r[4], (short)r[5], (short)r[6], (short)r[7],
                 (short)r[8], (short)r[9], (short)r[10], (short)r[11]};
    *(short4v*)&yTc[((blk + chunkA) * HW_ + pos) * 8 + 4] = v4;
    *(short8*)&yTc[((blk + chunkA + 1) * HW_ + pos) * 8] = v8;
  }
}

// ---------------------------------------------------------------------------
// K2 (v7): GEMM1 via MFMA bf16, gl_lds dbuf staging + LDS-bounced C-write.
// NEW: silu applied in epilogue for the z-half (jg>=192) -> zbb stores
// silu(z) pre-gated (ln2 drops its 48 __expf/thread). Computed in fp32 from
// un-rounded z -> one fewer bf16 round-trip on the gate.
// ---------------------------------------------------------------------------
__global__ __launch_bounds__(256) void k_gemm1(const unsigned short* __restrict__ yTc,
                                               const unsigned short* __restrict__ lwT,
                                               const float* __restrict__ lb,
                                               unsigned short* __restrict__ xpb,
                                               unsigned short* __restrict__ zbb) {
  __shared__ union {
    struct { unsigned short A[2][128 * 32]; unsigned short Y[2][128 * 32]; } st;
    unsigned short outT[128 * 132];
  } u;
  int b = blockIdx.y;
  int bx = blockIdx.x;                // 75 -> bijective XCD swizzle (q=9,r=3)
  int xcd = bx & 7, o8 = bx >> 3;
  int lg = (xcd < 3 ? xcd * 10 : 30 + (xcd - 3) * 9) + o8;
  int pt = lg / 3, jt = lg % 3;
  int pos0 = pt * 128, j0 = jt * 128;
  int tid = threadIdx.x, lane = tid & 63, wv = tid >> 6;
  int wm = wv & 1, wn = wv >> 1;
  int lr = lane & 15, lq = lane >> 4;

  const unsigned short* aSrc0 =
      lwT + (size_t)(j0 + wv * 32 + (lane >> 2)) * C_ + (lane & 3) * 8;
  const unsigned short* aSrc1 = aSrc0 + (size_t)16 * C_;
  const unsigned short* bSrc =
      yTc + (((size_t)b * 24 + wv) * HW_ + pos0) * 8 + lane * 8;

#define STAGE(BF, T)                                                             \
  {                                                                              \
    __builtin_amdgcn_global_load_lds((g_u32*)(aSrc0 + (T) * 32),                 \
                                     (l_u32*)(&u.st.A[BF][(wv * 2) * 16 * 32]), 16, 0, 0); \
    __builtin_amdgcn_global_load_lds((g_u32*)(aSrc1 + (T) * 32),                 \
                                     (l_u32*)(&u.st.A[BF][(wv * 2 + 1) * 16 * 32]), 16, 0, 0); \
    __builtin_amdgcn_global_load_lds((g_u32*)(bSrc + (size_t)((T) * 4) * HW_ * 8), \
                                     (l_u32*)(&u.st.Y[BF][wv * 1024]), 16, 0, 0); \
    __builtin_amdgcn_global_load_lds((g_u32*)(bSrc + (size_t)((T) * 4) * HW_ * 8 + 512), \
                                     (l_u32*)(&u.st.Y[BF][wv * 1024 + 512]), 16, 0, 0); \
  }

  STAGE(0, 0);
  f32x4 acc[4][4] = {};
#pragma unroll
  for (int t = 0; t < 6; ++t) {
    __syncthreads();
    int bf = t & 1;
    short8 af[4], bv[4];
#pragma unroll
    for (int m = 0; m < 4; ++m)
      af[m] = *(const short8*)&u.st.A[bf][(wm * 64 + m * 16 + lr) * 32 + lq * 8];
#pragma unroll
    for (int n = 0; n < 4; ++n)
      bv[n] = *(const short8*)&u.st.Y[bf][lq * 1024 + (wn * 64 + n * 16 + lr) * 8];
    if (t < 5) STAGE((t + 1) & 1, t + 1);
#pragma unroll
    for (int m = 0; m < 4; ++m)
#pragma unroll
      for (int n = 0; n < 4; ++n)
        acc[m][n] = __builtin_amdgcn_mfma_f32_16x16x32_bf16(af[m], bv[n], acc[m][n], 0, 0, 0);
  }
#undef STAGE

  __syncthreads();  // all LDS reads done; reuse as outT
#pragma unroll
  for (int m = 0; m < 4; ++m) {
    int jl0 = wm * 64 + m * 16 + lq * 4;
#pragma unroll
    for (int r = 0; r < 4; ++r) {
      int jg = j0 + jl0 + r;
      float bias = lb[jg];
#pragma unroll
      for (int n = 0; n < 4; ++n) {
        int pl = wn * 64 + n * 16 + lr;
        float v = acc[m][n][r] + bias;
        if (jg >= C_) v = v / (1.0f + __expf(-v));   // pre-gate: store silu(z)
        u.outT[(jl0 + r) * 132 + pl] = f2bf(v);
      }
    }
  }
  __syncthreads();
  for (int uu = tid; uu < 2048; uu += 256) {
    int jl = uu >> 4, pc = uu & 15;
    int pos = pos0 + pc * 8;
    if (pos < HW_) {
      int jg = j0 + jl;
      unsigned short* base = (jg < C_) ? (xpb + ((size_t)b * C_ + jg) * HW_)
                                       : (zbb + ((size_t)b * C_ + (jg - C_)) * HW_);
      *(short8*)&base[pos] = *(const short8*)&u.outT[jl * 132 + pc * 8];
    }
  }
}

// ---------------------------------------------------------------------------
// K4 (v7): spectral sandwich, TWO planes per 512-thread block.
// ---------------------------------------------------------------------------
__global__ __launch_bounds__(512) void k_spec(const unsigned short* __restrict__ xpb,
                                              const unsigned short* __restrict__ cosb,
                                              const unsigned short* __restrict__ cosbT,
                                              const float* __restrict__ wexp,
                                              unsigned short* __restrict__ sb) {
  constexpr int LDT = 72;
  __shared__ unsigned short sC[64 * LDT];       // [n][h] shared
  __shared__ unsigned short sCt[64 * LDT];      // [h][n] shared
  __shared__ unsigned short sP[2][64 * LDT];    // per-plane
  __shared__ unsigned short sT[2][64 * LDT];    // per-plane
  __shared__ unsigned short sWb[2][56 * 60];    // per-plane gate, bf16
  const int tid = threadIdx.x;
  const int bc0 = blockIdx.x * 2;

  for (int u = tid; u < 1152; u += 512) {
    if (u < 576) *(short8*)&sC[u * 8] = *(const short8*)&cosb[u * 8];
    else *(short8*)&sCt[(u - 576) * 8] = *(const short8*)&cosbT[(u - 576) * 8];
  }
  for (int u = tid; u < 736; u += 512) {
    int pl = u < 368 ? 0 : 1, r = u - pl * 368;
    uint2* zp;
    if (r < 224) {
      int row = r >> 2, q = r & 3;
      zp = (uint2*)&sP[pl][row * LDT + 56 + q * 4];
    } else {
      int rr = r - 224;
      int row = 56 + rr / 18, q = rr - (rr / 18) * 18;
      zp = (uint2*)&sP[pl][row * LDT + q * 4];
    }
    *zp = make_uint2(0u, 0u);
  }
  for (int u = tid; u < 784; u += 512) {
    int pl = u < 392 ? 0 : 1, uu = u - pl * 392;
    int n = uu / 7, w0 = (uu - n * 7) * 8;
    const unsigned short* Pp = xpb + (size_t)(bc0 + pl) * HW_;
    *(short8*)&sP[pl][n * LDT + w0] = *(const short8*)&Pp[n * 56 + w0];
  }
  for (int u = tid; u < 1568; u += 512) {
    int pl = u < 784 ? 0 : 1, uu = u - pl * 784;
    int n = uu / 14, m4 = (uu - n * 14) * 4;
    const float* Wp = wexp + (size_t)((bc0 + pl) % C_) * HW_;
    float4 wf = *(const float4*)&Wp[n * 56 + m4];
    short4v pk = {(short)f2bf(wf.x), (short)f2bf(wf.y),
                  (short)f2bf(wf.z), (short)f2bf(wf.w)};
    *(short4v*)&sWb[pl][n * 60 + m4] = pk;
  }
  __syncthreads();

  const int lane = tid & 63, wv = tid >> 6;
  const int pl = wv >> 2, wq = wv & 3;
  const int wm = wq & 1, wn = wq >> 1;
  const int lr = lane & 15, lk = lane >> 4;
  const int rt0 = wm * 2, ct0 = wn * 2;
  const unsigned short* sPp = sP[pl];
  unsigned short* sTp = sT[pl];
  const unsigned short* sWp = sWb[pl];
  short8 af[2][2], bg[2][2];
  f32x4 acc[2][2];

#define LOADFRAGS(Ab, Bb)                                                        \
  {                                                                              \
    _Pragma("unroll") for (int i = 0; i < 2; ++i) {                              \
      _Pragma("unroll") for (int k = 0; k < 2; ++k) {                            \
        af[i][k] = *(const short8*)&Ab[((rt0 + i) * 16 + lr) * LDT + k * 32 + lk * 8]; \
        bg[i][k] = *(const short8*)&Bb[((ct0 + i) * 16 + lr) * LDT + k * 32 + lk * 8]; \
      }                                                                          \
    }                                                                            \
  }
#define DOMFMA()                                                                 \
  {                                                                              \
    _Pragma("unroll") for (int i = 0; i < 2; ++i) {                              \
      _Pragma("unroll") for (int j = 0; j < 2; ++j) {                            \
        acc[i][j] = {};                                                          \
        acc[i][j] = __builtin_amdgcn_mfma_f32_16x16x32_bf16(af[i][0], bg[j][0], acc[i][j], 0, 0, 0); \
        acc[i][j] = __builtin_amdgcn_mfma_f32_16x16x32_bf16(af[i][1], bg[j][1], acc[i][j], 0, 0, 0); \
      }                                                                          \
    }                                                                            \
  }

  // stage 1
  LOADFRAGS(sPp, sC);
  DOMFMA();
#pragma unroll
  for (int i = 0; i < 2; ++i)
#pragma unroll
    for (int j = 0; j < 2; ++j) {
      int h0 = (rt0 + i) * 16 + lk * 4;
      int m = (ct0 + j) * 16 + lr;
      short4v pk;
#pragma unroll
      for (int r = 0; r < 4; ++r) pk[r] = (short)f2bf(acc[i][j][r]);
      *(short4v*)&sTp[m * LDT + h0] = pk;
    }
  __syncthreads();

  // stage 2
  LOADFRAGS(sC, sTp);
  __syncthreads();
  DOMFMA();
#pragma unroll
  for (int i = 0; i < 2; ++i)
#pragma unroll
    for (int j = 0; j < 2; ++j) {
      int n0 = (rt0 + i) * 16 + lk * 4;
      int m = (ct0 + j) * 16 + lr;
      int mc = m < 56 ? m : 55;
      short4v pk;
#pragma unroll
      for (int r = 0; r < 4; ++r) {
        int n = n0 + r;
        int nc = n < 56 ? n : 55;
        pk[r] = (short)f2bf(acc[i][j][r] * bf2f(sWp[nc * 60 + mc]));
      }
      *(short4v*)&sTp[m * LDT + n0] = pk;
    }
  __syncthreads();

  // stage 3
  LOADFRAGS(sCt, sTp);
  __syncthreads();
  DOMFMA();
#pragma unroll
  for (int i = 0; i < 2; ++i)
#pragma unroll
    for (int j = 0; j < 2; ++j)
#pragma unroll
      for (int r = 0; r < 4; ++r)
        sTp[((rt0 + i) * 16 + lk * 4 + r) * LDT + (ct0 + j) * 16 + lr] = f2bf(acc[i][j][r]);
  __syncthreads();

  // stage 4
  LOADFRAGS(sTp, sCt);
  DOMFMA();
  unsigned short* So = sb + (size_t)(bc0 + pl) * HW_;
#pragma unroll
  for (int i = 0; i < 2; ++i)
#pragma unroll
    for (int j = 0; j < 2; ++j) {
      int w = (ct0 + j) * 16 + lr;
      if (w < 56) {
#pragma unroll
        for (int r = 0; r < 4; ++r) {
          int h = (rt0 + i) * 16 + lk * 4 + r;
          if (h < 56) So[h * 56 + w] = f2bf(acc[i][j][r]);
        }
      }
    }
#undef LOADFRAGS
#undef DOMFMA
}

// ---------------------------------------------------------------------------
// K5 (v8): LayerNorm (bf16 s) -> gate multiply (zbb holds pre-gated silu(z))
// -> GEMM2 via MFMA bf16. The 48 __expf/thread moved to gemm1's epilogue.
// ---------------------------------------------------------------------------
__global__ __launch_bounds__(256) void k_ln2(const unsigned short* __restrict__ s,
                                             const unsigned short* __restrict__ z,
                                             const float* __restrict__ gamma,
                                             const float* __restrict__ beta,
                                             const unsigned short* __restrict__ owT,
                                             const float* __restrict__ ob,
                                             float* __restrict__ out) {
  __shared__ unsigned short act[64 * 200];
  __shared__ float red[8][64];
  __shared__ float smu[64], srs[64];
  int b = blockIdx.y, pt = blockIdx.x;
  int tid = threadIdx.x, lane = tid & 63, wv = tid >> 6;
  int p = lane, cr = wv;
  const unsigned short* sp = s + (size_t)b * CHW_ + (size_t)(48 * cr) * HW_ + pt * 64 + p;
  const unsigned short* zp = z + (size_t)b * CHW_ + (size_t)(48 * cr) * HW_ + pt * 64 + p;
  float sv[48];
  float sum = 0.f, sq = 0.f;
#pragma unroll
  for (int i = 0; i < 48; ++i) {
    float v = bf2f(sp[(size_t)i * HW_]);
    sv[i] = v;
    sum += v;
    sq = fmaf(v, v, sq);
  }
  red[cr][p] = sum;
  red[4 + cr][p] = sq;
  __syncthreads();
  if (tid < 64) {
    float s1 = red[0][tid] + red[1][tid] + red[2][tid] + red[3][tid];
    float s2 = red[4][tid] + red[5][tid] + red[6][tid] + red[7][tid];
    float mu = s1 * (1.0f / 192.0f);
    float var = s2 * (1.0f / 192.0f) - mu * mu;
    smu[tid] = mu;
    srs[tid] = rsqrtf(var + 1e-5f);
  }
  __syncthreads();
  float mu = smu[p], rs = srs[p];
#pragma unroll
  for (int q = 0; q < 6; ++q) {
    short8 vv;
#pragma unroll
    for (int e = 0; e < 8; ++e) {
      int i = 8 * q + e;
      int c = 48 * cr + i;
      float v = (sv[i] - mu) * rs * gamma[c] + beta[c];
      v *= bf2f(zp[(size_t)i * HW_]);   // zbb holds silu(z) already
      vv[e] = (short)f2bf(v);
    }
    *(short8*)&act[p * 200 + ((48 * cr + 8 * q) ^ swz(p))] = vv;
  }
  __syncthreads();

  f32x4 acc[3][4] = {};
  const unsigned short* ap = owT + (size_t)(wv * 48 + (lane & 15)) * C_ + (lane >> 4) * 8;
#pragma unroll
  for (int kk = 0; kk < C_; kk += 32) {
    short8 af[3], bf[4];
#pragma unroll
    for (int m = 0; m < 3; ++m) af[m] = *(const short8*)(ap + m * 16 * C_ + kk);
#pragma unroll
    for (int n = 0; n < 4; ++n) {
      int row = (lane & 15) + 16 * n;
      int co = (kk + (lane >> 4) * 8) ^ swz(row);
      bf[n] = *(const short8*)&act[row * 200 + co];
    }
#pragma unroll
    for (int m = 0; m < 3; ++m)
#pragma unroll
      for (int n = 0; n < 4; ++n)
        acc[m][n] = __builtin_amdgcn_mfma_f32_16x16x32_bf16(af[m], bf[n], acc[m][n], 0, 0, 0);
  }

  float* op = out + (size_t)b * CHW_ + pt * 64;
#pragma unroll
  for (int m = 0; m < 3; ++m) {
    int jb = wv * 48 + m * 16 + (lane >> 4) * 4;
#pragma unroll
    for (int r = 0; r < 4; ++r) {
      int j = jb + r;
      float bias = ob[j];
#pragma unroll
      for (int n = 0; n < 4; ++n) {
        int pos = n * 16 + (lane & 15);
        op[(size_t)j * HW_ + pos] = acc[m][n][r] + bias;
      }
    }
  }
}

}  // namespace

extern "C" void kernel_launch(void* const* d_in, const int* in_sizes, int n_in,
                              void* d_out, int out_size, void* d_ws, size_t ws_size,
                              hipStream_t stream) {
  const float* x = (const float*)d_in[0];
  const float* dww = (const float*)d_in[1];
  const float* dwb = (const float*)d_in[2];
  const float* lw = (const float*)d_in[3];
  const float* lb = (const float*)d_in[4];
  const float* tkw = (const float*)d_in[5];
  const float* tkb = (const float*)d_in[6];
  const float* fe = (const float*)d_in[7];
  const float* gamma = (const float*)d_in[8];
  const float* beta = (const float*)d_in[9];
  const float* ow = (const float*)d_in[10];
  const float* obias = (const float*)d_in[11];
  float* out = (float*)d_out;

  float* ws = (float*)d_ws;
  unsigned short* cosb = (unsigned short*)ws;           // 4608 u16
  unsigned short* cosbT = cosb + 4608;                  // 4608 u16
  float* wexp = (float*)(cosbT + 4608);                 // 602112 f
  unsigned short* zbb = (unsigned short*)(wexp + CHW_); // 38535168 u16
  unsigned short* lwT = zbb + (size_t)B_ * CHW_;        // 73728 u16
  unsigned short* owT = lwT + 384 * C_;                 // 36864 u16
  unsigned short* yTc = owT + C_ * C_;                  // 38535168 u16 (chunked)
  unsigned short* xpb = yTc + (size_t)B_ * CHW_;        // 38535168 u16
  unsigned short* sb = xpb + (size_t)B_ * CHW_;         // 38535168 u16

  hipLaunchKernelGGL(k_tables, dim3(18), dim3(256), 0, stream, cosb, cosbT);
  hipLaunchKernelGGL(k_wexp, dim3(HW_ / 16), dim3(192), 0, stream, fe, tkw, tkb, wexp);
  hipLaunchKernelGGL(k_prep_w, dim3(432), dim3(256), 0, stream, lw, ow, lwT, owT);
  hipLaunchKernelGGL(k_convt, dim3(HW_ / 64, 4, B_), dim3(256), 0, stream, x, dww, dwb, yTc);
  hipLaunchKernelGGL(k_gemm1, dim3(75, B_), dim3(256), 0, stream, yTc, lwT, lb, xpb, zbb);
  hipLaunchKernelGGL(k_spec, dim3(B_ * C_ / 2), dim3(512), 0, stream, xpb, cosb, cosbT, wexp, sb);
  hipLaunchKernelGGL(k_ln2, dim3(HW_ / 64, B_), dim3(256), 0, stream, sb, zbb, gamma, beta,
                     owT, obias, out);
}

// Round 29
// 376.096 us; speedup vs baseline: 1.0592x; 1.0592x over previous
//
#include <hip/hip_runtime.h>
#include <math.h>

namespace {

constexpr int B_ = 64;
constexpr int C_ = 192;
constexpr int H_ = 56;
constexpr int W_ = 56;
constexpr int HW_ = H_ * W_;          // 3136
constexpr int CHW_ = C_ * HW_;        // 602112
constexpr float PI_F = 3.14159265358979323846f;

typedef __attribute__((ext_vector_type(8))) short short8;
typedef __attribute__((ext_vector_type(4))) short short4v;
typedef __attribute__((ext_vector_type(4))) float f32x4;

typedef const __attribute__((address_space(1))) unsigned int g_u32;
typedef __attribute__((address_space(3))) unsigned int l_u32;

__device__ inline unsigned short f2bf(float f) {
  union { float f; unsigned u; } v{f};
  unsigned r = v.u + 0x7FFFu + ((v.u >> 16) & 1u);
  return (unsigned short)(r >> 16);
}
__device__ inline float bf2f(unsigned short s) {
  union { unsigned u; float f; } v;
  v.u = ((unsigned)s) << 16;
  return v.f;
}

// XOR swizzle for [row][c] bf16 tiles, row stride 200 elems (16B granular)
__device__ inline int swz(int row) { return ((row >> 1) & 7) << 3; }

// ---------------------------------------------------------------------------
// K0 (v2): DCT-II basis, bf16, BOTH orientations, padded [64][72] LDS image.
// ---------------------------------------------------------------------------
__global__ void k_tables(unsigned short* __restrict__ cosb,
                         unsigned short* __restrict__ cosbT) {
  int i = blockIdx.x * 256 + threadIdx.x;
  if (i >= 64 * 72) return;
  int r = i / 72, q = i - r * 72;
  unsigned short v0 = 0, v1 = 0;
  if (r < 56 && q < 56) {
    float a0 = cosf(((float)r * (((float)q + 0.5f) / 56.0f)) * PI_F) * 0.18898223650461362f;
    if (r == 0) a0 *= 0.7071067811865476f;
    v0 = f2bf(a0);
    float a1 = cosf(((float)q * (((float)r + 0.5f) / 56.0f)) * PI_F) * 0.18898223650461362f;
    if (q == 0) a1 *= 0.7071067811865476f;
    v1 = f2bf(a1);
  }
  cosb[i] = v0;   // [n][h]
  cosbT[i] = v1;  // [h][n]
}

// ---------------------------------------------------------------------------
// K_wexp: wexp[c][hw] = exp(-relu(fe@tok_w+tok_b) * (n^2+m^2))
// ---------------------------------------------------------------------------
__global__ __launch_bounds__(192) void k_wexp(const float* __restrict__ fe,
                                              const float* __restrict__ tkw,
                                              const float* __restrict__ tkb,
                                              float* __restrict__ wexp) {
  __shared__ float sfe[16][C_];
  int hw0 = blockIdx.x * 16;
  int t = threadIdx.x;
  for (int p = 0; p < 16; ++p) sfe[p][t] = fe[(size_t)(hw0 + p) * C_ + t];
  __syncthreads();
  float acc[16];
#pragma unroll
  for (int p = 0; p < 16; ++p) acc[p] = 0.f;
  for (int i = 0; i < C_; ++i) {
    float wv = tkw[i * C_ + t];
#pragma unroll
    for (int p = 0; p < 16; ++p) acc[p] = fmaf(sfe[p][i], wv, acc[p]);
  }
  float bias = tkb[t];
  const float step = PI_F / 56.0f;
#pragma unroll
  for (int p = 0; p < 16; ++p) {
    int hw = hw0 + p;
    int hh = hw / W_;
    int ww = hw - hh * W_;
    float nh = step * (float)hh;
    float nm = step * (float)ww;
    float a = nh * nh + nm * nm;
    float k = fmaxf(acc[p] + bias, 0.0f);
    wexp[(size_t)t * HW_ + hw] = expf(-k * a);
  }
}

// ---------------------------------------------------------------------------
// K_prep_w: lwT[j][c] = bf16(lin_w[c][j]), owT[j][c] = bf16(out_w[c][j])
// ---------------------------------------------------------------------------
__global__ __launch_bounds__(256) void k_prep_w(const float* __restrict__ lw,
                                                const float* __restrict__ ow,
                                                unsigned short* __restrict__ lwT,
                                                unsigned short* __restrict__ owT) {
  int i = blockIdx.x * 256 + threadIdx.x;
  if (i < 384 * 192) {
    int j = i / 192, c = i - j * 192;
    lwT[i] = f2bf(lw[c * 384 + j]);
  } else if (i < 384 * 192 + 192 * 192) {
    int k = i - 384 * 192;
    int j = k / 192, c = k - j * 192;
    owT[k] = f2bf(ow[c * 192 + j]);
  }
}

// ---------------------------------------------------------------------------
// K1 (v8): depthwise 3x3 conv via async global_load_lds staging, 48 ch/block.
// ---------------------------------------------------------------------------
__global__ __launch_bounds__(256) void k_convt(const float* __restrict__ x,
                                               const float* __restrict__ dww,
                                               const float* __restrict__ dwb,
                                               unsigned short* __restrict__ yTc) {
  __shared__ float win[48 * 192];
  __shared__ float swt[48 * 9];
  __shared__ float sbi[48];
  int tid = threadIdx.x;
  int pt = blockIdx.x, qr = blockIdx.y, b = blockIdx.z;
  int c0 = qr * 48;
  for (int i = tid; i < 48 * 9; i += 256) swt[i] = dww[c0 * 9 + i];
  if (tid < 48) sbi[tid] = dwb[c0 + tid];

  int lane = tid & 63, wv = tid >> 6;
  int ws = pt * 64 - 60;
  int srcf = ws + lane * 4;
  srcf = srcf < 0 ? 0 : (srcf > HW_ - 4 ? HW_ - 4 : srcf);
  const float* xb = x + (size_t)b * CHW_ + (size_t)c0 * HW_;
  if (lane < 48) {
    for (int cc = wv; cc < 48; cc += 4) {
      __builtin_amdgcn_global_load_lds((g_u32*)(xb + (size_t)cc * HW_ + srcf),
                                       (l_u32*)(win + cc * 192), 16, 0, 0);
    }
  }
  __syncthreads();  // drains vmcnt

  int p = tid & 63, chg = tid >> 6;
  int pos = pt * 64 + p;
  int h = pos / 56, w = pos - h * 56;
  float mN = h > 0 ? 1.f : 0.f, mP = h < 55 ? 1.f : 0.f;
  float mL = w > 0 ? 1.f : 0.f, mR = w < 55 ? 1.f : 0.f;
  int base = p + 60;
  int l0 = chg * 12;
  unsigned short r[12];
#pragma unroll
  for (int e = 0; e < 12; ++e) {
    int cc = l0 + e;
    const float* wr = &win[cc * 192];
    const float* w9 = &swt[cc * 9];
    float a = sbi[cc];
    {  // row -1
      float wa = w9[0] * mN, wb = w9[1] * mN, wc = w9[2] * mN;
      float v0 = wr[base - 57] * mL, v1 = wr[base - 56], v2 = wr[base - 55] * mR;
      a = fmaf(v0, wa, fmaf(v1, wb, fmaf(v2, wc, a)));
    }
    {  // row 0
      float v0 = wr[base - 1] * mL, v1 = wr[base], v2 = wr[base + 1] * mR;
      a = fmaf(v0, w9[3], fmaf(v1, w9[4], fmaf(v2, w9[5], a)));
    }
    {  // row +1
      float wa = w9[6] * mP, wb = w9[7] * mP, wc = w9[8] * mP;
      float v0 = wr[base + 55] * mL, v1 = wr[base + 56], v2 = wr[base + 57] * mR;
      a = fmaf(v0, wa, fmaf(v1, wb, fmaf(v2, wc, a)));
    }
    r[e] = f2bf(a);
  }
  int chunkA = (c0 >> 3) + (l0 >> 3);
  size_t blk = (size_t)b * 24;
  if ((chg & 1) == 0) {
    short8 v8 = {(short)r[0], (short)r[1], (short)r[2], (short)r[3],
                 (short)r[4], (short)r[5], (short)r[6], (short)r[7]};
    short4v v4 = {(short)r[8], (short)r[9], (short)r[10], (short)r[11]};
    *(short8*)&yTc[((blk + chunkA) * HW_ + pos) * 8] = v8;
    *(short4v*)&yTc[((blk + chunkA + 1) * HW_ + pos) * 8] = v4;
  } else {
    short4v v4 = {(short)r[0], (short)r[1], (short)r[2], (short)r[3]};
    short8 v8 = {(short)r[4], (short)r[5], (short)r[6], (short)r[7],
                 (short)r[8], (short)r[9], (short)r[10], (short)r[11]};
    *(short4v*)&yTc[((blk + chunkA) * HW_ + pos) * 8 + 4] = v4;
    *(short8*)&yTc[((blk + chunkA + 1) * HW_ + pos) * 8] = v8;
  }
}

// ---------------------------------------------------------------------------
// K2 (v6): GEMM1 via MFMA bf16, gl_lds dbuf staging + LDS-bounced C-write.
// (R28's silu-fold reverted: epilogue exp sits between barriers on the
// critical path at 28% occupancy -> +10us; cost exceeded ln2's saving.)
// ---------------------------------------------------------------------------
__global__ __launch_bounds__(256) void k_gemm1(const unsigned short* __restrict__ yTc,
                                               const unsigned short* __restrict__ lwT,
                                               const float* __restrict__ lb,
                                               unsigned short* __restrict__ xpb,
                                               unsigned short* __restrict__ zbb) {
  __shared__ union {
    struct { unsigned short A[2][128 * 32]; unsigned short Y[2][128 * 32]; } st;
    unsigned short outT[128 * 132];
  } u;
  int b = blockIdx.y;
  int bx = blockIdx.x;                // 75 -> bijective XCD swizzle (q=9,r=3)
  int xcd = bx & 7, o8 = bx >> 3;
  int lg = (xcd < 3 ? xcd * 10 : 30 + (xcd - 3) * 9) + o8;
  int pt = lg / 3, jt = lg % 3;
  int pos0 = pt * 128, j0 = jt * 128;
  int tid = threadIdx.x, lane = tid & 63, wv = tid >> 6;
  int wm = wv & 1, wn = wv >> 1;
  int lr = lane & 15, lq = lane >> 4;

  const unsigned short* aSrc0 =
      lwT + (size_t)(j0 + wv * 32 + (lane >> 2)) * C_ + (lane & 3) * 8;
  const unsigned short* aSrc1 = aSrc0 + (size_t)16 * C_;
  const unsigned short* bSrc =
      yTc + (((size_t)b * 24 + wv) * HW_ + pos0) * 8 + lane * 8;

#define STAGE(BF, T)                                                             \
  {                                                                              \
    __builtin_amdgcn_global_load_lds((g_u32*)(aSrc0 + (T) * 32),                 \
                                     (l_u32*)(&u.st.A[BF][(wv * 2) * 16 * 32]), 16, 0, 0); \
    __builtin_amdgcn_global_load_lds((g_u32*)(aSrc1 + (T) * 32),                 \
                                     (l_u32*)(&u.st.A[BF][(wv * 2 + 1) * 16 * 32]), 16, 0, 0); \
    __builtin_amdgcn_global_load_lds((g_u32*)(bSrc + (size_t)((T) * 4) * HW_ * 8), \
                                     (l_u32*)(&u.st.Y[BF][wv * 1024]), 16, 0, 0); \
    __builtin_amdgcn_global_load_lds((g_u32*)(bSrc + (size_t)((T) * 4) * HW_ * 8 + 512), \
                                     (l_u32*)(&u.st.Y[BF][wv * 1024 + 512]), 16, 0, 0); \
  }

  STAGE(0, 0);
  f32x4 acc[4][4] = {};
#pragma unroll
  for (int t = 0; t < 6; ++t) {
    __syncthreads();
    int bf = t & 1;
    short8 af[4], bv[4];
#pragma unroll
    for (int m = 0; m < 4; ++m)
      af[m] = *(const short8*)&u.st.A[bf][(wm * 64 + m * 16 + lr) * 32 + lq * 8];
#pragma unroll
    for (int n = 0; n < 4; ++n)
      bv[n] = *(const short8*)&u.st.Y[bf][lq * 1024 + (wn * 64 + n * 16 + lr) * 8];
    if (t < 5) STAGE((t + 1) & 1, t + 1);
#pragma unroll
    for (int m = 0; m < 4; ++m)
#pragma unroll
      for (int n = 0; n < 4; ++n)
        acc[m][n] = __builtin_amdgcn_mfma_f32_16x16x32_bf16(af[m], bv[n], acc[m][n], 0, 0, 0);
  }
#undef STAGE

  __syncthreads();  // all LDS reads done; reuse as outT
#pragma unroll
  for (int m = 0; m < 4; ++m) {
    int jl0 = wm * 64 + m * 16 + lq * 4;
#pragma unroll
    for (int r = 0; r < 4; ++r) {
      float bias = lb[j0 + jl0 + r];
#pragma unroll
      for (int n = 0; n < 4; ++n) {
        int pl = wn * 64 + n * 16 + lr;
        u.outT[(jl0 + r) * 132 + pl] = f2bf(acc[m][n][r] + bias);
      }
    }
  }
  __syncthreads();
  for (int uu = tid; uu < 2048; uu += 256) {
    int jl = uu >> 4, pc = uu & 15;
    int pos = pos0 + pc * 8;
    if (pos < HW_) {
      int jg = j0 + jl;
      unsigned short* base = (jg < C_) ? (xpb + ((size_t)b * C_ + jg) * HW_)
                                       : (zbb + ((size_t)b * C_ + (jg - C_)) * HW_);
      *(short8*)&base[pos] = *(const short8*)&u.outT[jl * 132 + pc * 8];
    }
  }
}

// ---------------------------------------------------------------------------
// K4 (v7): spectral sandwich, TWO planes per 512-thread block.
// ---------------------------------------------------------------------------
__global__ __launch_bounds__(512) void k_spec(const unsigned short* __restrict__ xpb,
                                              const unsigned short* __restrict__ cosb,
                                              const unsigned short* __restrict__ cosbT,
                                              const float* __restrict__ wexp,
                                              unsigned short* __restrict__ sb) {
  constexpr int LDT = 72;
  __shared__ unsigned short sC[64 * LDT];       // [n][h] shared
  __shared__ unsigned short sCt[64 * LDT];      // [h][n] shared
  __shared__ unsigned short sP[2][64 * LDT];    // per-plane
  __shared__ unsigned short sT[2][64 * LDT];    // per-plane
  __shared__ unsigned short sWb[2][56 * 60];    // per-plane gate, bf16
  const int tid = threadIdx.x;
  const int bc0 = blockIdx.x * 2;

  for (int u = tid; u < 1152; u += 512) {
    if (u < 576) *(short8*)&sC[u * 8] = *(const short8*)&cosb[u * 8];
    else *(short8*)&sCt[(u - 576) * 8] = *(const short8*)&cosbT[(u - 576) * 8];
  }
  for (int u = tid; u < 736; u += 512) {
    int pl = u < 368 ? 0 : 1, r = u - pl * 368;
    uint2* zp;
    if (r < 224) {
      int row = r >> 2, q = r & 3;
      zp = (uint2*)&sP[pl][row * LDT + 56 + q * 4];
    } else {
      int rr = r - 224;
      int row = 56 + rr / 18, q = rr - (rr / 18) * 18;
      zp = (uint2*)&sP[pl][row * LDT + q * 4];
    }
    *zp = make_uint2(0u, 0u);
  }
  for (int u = tid; u < 784; u += 512) {
    int pl = u < 392 ? 0 : 1, uu = u - pl * 392;
    int n = uu / 7, w0 = (uu - n * 7) * 8;
    const unsigned short* Pp = xpb + (size_t)(bc0 + pl) * HW_;
    *(short8*)&sP[pl][n * LDT + w0] = *(const short8*)&Pp[n * 56 + w0];
  }
  for (int u = tid; u < 1568; u += 512) {
    int pl = u < 784 ? 0 : 1, uu = u - pl * 784;
    int n = uu / 14, m4 = (uu - n * 14) * 4;
    const float* Wp = wexp + (size_t)((bc0 + pl) % C_) * HW_;
    float4 wf = *(const float4*)&Wp[n * 56 + m4];
    short4v pk = {(short)f2bf(wf.x), (short)f2bf(wf.y),
                  (short)f2bf(wf.z), (short)f2bf(wf.w)};
    *(short4v*)&sWb[pl][n * 60 + m4] = pk;
  }
  __syncthreads();

  const int lane = tid & 63, wv = tid >> 6;
  const int pl = wv >> 2, wq = wv & 3;
  const int wm = wq & 1, wn = wq >> 1;
  const int lr = lane & 15, lk = lane >> 4;
  const int rt0 = wm * 2, ct0 = wn * 2;
  const unsigned short* sPp = sP[pl];
  unsigned short* sTp = sT[pl];
  const unsigned short* sWp = sWb[pl];
  short8 af[2][2], bg[2][2];
  f32x4 acc[2][2];

#define LOADFRAGS(Ab, Bb)                                                        \
  {                                                                              \
    _Pragma("unroll") for (int i = 0; i < 2; ++i) {                              \
      _Pragma("unroll") for (int k = 0; k < 2; ++k) {                            \
        af[i][k] = *(const short8*)&Ab[((rt0 + i) * 16 + lr) * LDT + k * 32 + lk * 8]; \
        bg[i][k] = *(const short8*)&Bb[((ct0 + i) * 16 + lr) * LDT + k * 32 + lk * 8]; \
      }                                                                          \
    }                                                                            \
  }
#define DOMFMA()                                                                 \
  {                                                                              \
    _Pragma("unroll") for (int i = 0; i < 2; ++i) {                              \
      _Pragma("unroll") for (int j = 0; j < 2; ++j) {                            \
        acc[i][j] = {};                                                          \
        acc[i][j] = __builtin_amdgcn_mfma_f32_16x16x32_bf16(af[i][0], bg[j][0], acc[i][j], 0, 0, 0); \
        acc[i][j] = __builtin_amdgcn_mfma_f32_16x16x32_bf16(af[i][1], bg[j][1], acc[i][j], 0, 0, 0); \
      }                                                                          \
    }                                                                            \
  }

  // stage 1
  LOADFRAGS(sPp, sC);
  DOMFMA();
#pragma unroll
  for (int i = 0; i < 2; ++i)
#pragma unroll
    for (int j = 0; j < 2; ++j) {
      int h0 = (rt0 + i) * 16 + lk * 4;
      int m = (ct0 + j) * 16 + lr;
      short4v pk;
#pragma unroll
      for (int r = 0; r < 4; ++r) pk[r] = (short)f2bf(acc[i][j][r]);
      *(short4v*)&sTp[m * LDT + h0] = pk;
    }
  __syncthreads();

  // stage 2
  LOADFRAGS(sC, sTp);
  __syncthreads();
  DOMFMA();
#pragma unroll
  for (int i = 0; i < 2; ++i)
#pragma unroll
    for (int j = 0; j < 2; ++j) {
      int n0 = (rt0 + i) * 16 + lk * 4;
      int m = (ct0 + j) * 16 + lr;
      int mc = m < 56 ? m : 55;
      short4v pk;
#pragma unroll
      for (int r = 0; r < 4; ++r) {
        int n = n0 + r;
        int nc = n < 56 ? n : 55;
        pk[r] = (short)f2bf(acc[i][j][r] * bf2f(sWp[nc * 60 + mc]));
      }
      *(short4v*)&sTp[m * LDT + n0] = pk;
    }
  __syncthreads();

  // stage 3
  LOADFRAGS(sCt, sTp);
  __syncthreads();
  DOMFMA();
#pragma unroll
  for (int i = 0; i < 2; ++i)
#pragma unroll
    for (int j = 0; j < 2; ++j)
#pragma unroll
      for (int r = 0; r < 4; ++r)
        sTp[((rt0 + i) * 16 + lk * 4 + r) * LDT + (ct0 + j) * 16 + lr] = f2bf(acc[i][j][r]);
  __syncthreads();

  // stage 4
  LOADFRAGS(sTp, sCt);
  DOMFMA();
  unsigned short* So = sb + (size_t)(bc0 + pl) * HW_;
#pragma unroll
  for (int i = 0; i < 2; ++i)
#pragma unroll
    for (int j = 0; j < 2; ++j) {
      int w = (ct0 + j) * 16 + lr;
      if (w < 56) {
#pragma unroll
        for (int r = 0; r < 4; ++r) {
          int h = (rt0 + i) * 16 + lk * 4 + r;
          if (h < 56) So[h * 56 + w] = f2bf(acc[i][j][r]);
        }
      }
    }
#undef LOADFRAGS
#undef DOMFMA
}

// ---------------------------------------------------------------------------
// K5 (v6): LayerNorm (bf16 s) -> silu-gate (bf16 z, __expf) -> GEMM2 MFMA.
// ---------------------------------------------------------------------------
__global__ __launch_bounds__(256) void k_ln2(const unsigned short* __restrict__ s,
                                             const unsigned short* __restrict__ z,
                                             const float* __restrict__ gamma,
                                             const float* __restrict__ beta,
                                             const unsigned short* __restrict__ owT,
                                             const float* __restrict__ ob,
                                             float* __restrict__ out) {
  __shared__ unsigned short act[64 * 200];
  __shared__ float red[8][64];
  __shared__ float smu[64], srs[64];
  int b = blockIdx.y, pt = blockIdx.x;
  int tid = threadIdx.x, lane = tid & 63, wv = tid >> 6;
  int p = lane, cr = wv;
  const unsigned short* sp = s + (size_t)b * CHW_ + (size_t)(48 * cr) * HW_ + pt * 64 + p;
  const unsigned short* zp = z + (size_t)b * CHW_ + (size_t)(48 * cr) * HW_ + pt * 64 + p;
  float sv[48];
  float sum = 0.f, sq = 0.f;
#pragma unroll
  for (int i = 0; i < 48; ++i) {
    float v = bf2f(sp[(size_t)i * HW_]);
    sv[i] = v;
    sum += v;
    sq = fmaf(v, v, sq);
  }
  red[cr][p] = sum;
  red[4 + cr][p] = sq;
  __syncthreads();
  if (tid < 64) {
    float s1 = red[0][tid] + red[1][tid] + red[2][tid] + red[3][tid];
    float s2 = red[4][tid] + red[5][tid] + red[6][tid] + red[7][tid];
    float mu = s1 * (1.0f / 192.0f);
    float var = s2 * (1.0f / 192.0f) - mu * mu;
    smu[tid] = mu;
    srs[tid] = rsqrtf(var + 1e-5f);
  }
  __syncthreads();
  float mu = smu[p], rs = srs[p];
#pragma unroll
  for (int q = 0; q < 6; ++q) {
    short8 vv;
#pragma unroll
    for (int e = 0; e < 8; ++e) {
      int i = 8 * q + e;
      int c = 48 * cr + i;
      float v = (sv[i] - mu) * rs * gamma[c] + beta[c];
      float zz = bf2f(zp[(size_t)i * HW_]);
      v *= zz / (1.0f + __expf(-zz));
      vv[e] = (short)f2bf(v);
    }
    *(short8*)&act[p * 200 + ((48 * cr + 8 * q) ^ swz(p))] = vv;
  }
  __syncthreads();

  f32x4 acc[3][4] = {};
  const unsigned short* ap = owT + (size_t)(wv * 48 + (lane & 15)) * C_ + (lane >> 4) * 8;
#pragma unroll
  for (int kk = 0; kk < C_; kk += 32) {
    short8 af[3], bf[4];
#pragma unroll
    for (int m = 0; m < 3; ++m) af[m] = *(const short8*)(ap + m * 16 * C_ + kk);
#pragma unroll
    for (int n = 0; n < 4; ++n) {
      int row = (lane & 15) + 16 * n;
      int co = (kk + (lane >> 4) * 8) ^ swz(row);
      bf[n] = *(const short8*)&act[row * 200 + co];
    }
#pragma unroll
    for (int m = 0; m < 3; ++m)
#pragma unroll
      for (int n = 0; n < 4; ++n)
        acc[m][n] = __builtin_amdgcn_mfma_f32_16x16x32_bf16(af[m], bf[n], acc[m][n], 0, 0, 0);
  }

  float* op = out + (size_t)b * CHW_ + pt * 64;
#pragma unroll
  for (int m = 0; m < 3; ++m) {
    int jb = wv * 48 + m * 16 + (lane >> 4) * 4;
#pragma unroll
    for (int r = 0; r < 4; ++r) {
      int j = jb + r;
      float bias = ob[j];
#pragma unroll
      for (int n = 0; n < 4; ++n) {
        int pos = n * 16 + (lane & 15);
        op[(size_t)j * HW_ + pos] = acc[m][n][r] + bias;
      }
    }
  }
}

}  // namespace

extern "C" void kernel_launch(void* const* d_in, const int* in_sizes, int n_in,
                              void* d_out, int out_size, void* d_ws, size_t ws_size,
                              hipStream_t stream) {
  const float* x = (const float*)d_in[0];
  const float* dww = (const float*)d_in[1];
  const float* dwb = (const float*)d_in[2];
  const float* lw = (const float*)d_in[3];
  const float* lb = (const float*)d_in[4];
  const float* tkw = (const float*)d_in[5];
  const float* tkb = (const float*)d_in[6];
  const float* fe = (const float*)d_in[7];
  const float* gamma = (const float*)d_in[8];
  const float* beta = (const float*)d_in[9];
  const float* ow = (const float*)d_in[10];
  const float* obias = (const float*)d_in[11];
  float* out = (float*)d_out;

  float* ws = (float*)d_ws;
  unsigned short* cosb = (unsigned short*)ws;           // 4608 u16
  unsigned short* cosbT = cosb + 4608;                  // 4608 u16
  float* wexp = (float*)(cosbT + 4608);                 // 602112 f
  unsigned short* zbb = (unsigned short*)(wexp + CHW_); // 38535168 u16
  unsigned short* lwT = zbb + (size_t)B_ * CHW_;        // 73728 u16
  unsigned short* owT = lwT + 384 * C_;                 // 36864 u16
  unsigned short* yTc = owT + C_ * C_;                  // 38535168 u16 (chunked)
  unsigned short* xpb = yTc + (size_t)B_ * CHW_;        // 38535168 u16
  unsigned short* sb = xpb + (size_t)B_ * CHW_;         // 38535168 u16

  hipLaunchKernelGGL(k_tables, dim3(18), dim3(256), 0, stream, cosb, cosbT);
  hipLaunchKernelGGL(k_wexp, dim3(HW_ / 16), dim3(192), 0, stream, fe, tkw, tkb, wexp);
  hipLaunchKernelGGL(k_prep_w, dim3(432), dim3(256), 0, stream, lw, ow, lwT, owT);
  hipLaunchKernelGGL(k_convt, dim3(HW_ / 64, 4, B_), dim3(256), 0, stream, x, dww, dwb, yTc);
  hipLaunchKernelGGL(k_gemm1, dim3(75, B_), dim3(256), 0, stream, yTc, lwT, lb, xpb, zbb);
  hipLaunchKernelGGL(k_spec, dim3(B_ * C_ / 2), dim3(512), 0, stream, xpb, cosb, cosbT, wexp, sb);
  hipLaunchKernelGGL(k_ln2, dim3(HW_ / 64, B_), dim3(256), 0, stream, sb, zbb, gamma, beta,
                     owT, obias, out);
}